// Round 3
// baseline (203.750 us; speedup 1.0000x reference)
//
#include <hip/hip_runtime.h>
#include <hip/hip_bf16.h>
#include <math.h>

#define B_ 8
#define T_ 2048
#define C_ 1024
#define H_ 64
#define M_ (B_*T_)   // 16384 rows

typedef __attribute__((ext_vector_type(8))) short bf16x8;
typedef __attribute__((ext_vector_type(4))) float floatx4;

// fp32 -> bf16 round-to-nearest-even (used in cold paths)
static __device__ __forceinline__ unsigned short f2bf(float f) {
    union { float f; unsigned u; } v; v.f = f;
    unsigned r = v.u + 0x7fffu + ((v.u >> 16) & 1u);
    return (unsigned short)(r >> 16);
}
// fp32 -> bf16 round-half-up (2 VALU) for hot paths
static __device__ __forceinline__ unsigned short f2bf_fast(float f) {
    union { float f; unsigned u; } v; v.f = f;
    return (unsigned short)((v.u + 0x8000u) >> 16);
}
// pack two fp32 -> bf16 pair [hi|lo] in 3 VALU (add, add, v_perm)
static __device__ __forceinline__ unsigned pk2h(float lo, float hi) {
    union { float f; unsigned u; } a, b; a.f = lo; b.f = hi;
    return __builtin_amdgcn_perm(b.u + 0x8000u, a.u + 0x8000u, 0x07060302u);
}
static __device__ __forceinline__ bf16x8 cvt8(float4 f0, float4 f1) {
    union { uint4 u; bf16x8 v; } r;
    r.u.x = pk2h(f0.x, f0.y); r.u.y = pk2h(f0.z, f0.w);
    r.u.z = pk2h(f1.x, f1.y); r.u.w = pk2h(f1.z, f1.w);
    return r.v;
}

#define MFMA(a,b,c) __builtin_amdgcn_mfma_f32_16x16x32_bf16((a),(b),(c),0,0,0)

// ---------------------------------------------------------------------------
// Kernel 0: W prep. W{q,k,v}[1024,64] fp32 -> wt[192][1024] bf16 (transposed).
// ---------------------------------------------------------------------------
__global__ __launch_bounds__(256) void wprep_kernel(
    const float* __restrict__ Wq, const float* __restrict__ Wk,
    const float* __restrict__ Wv, unsigned short* __restrict__ wt)
{
    const int c = blockIdx.x;                 // 0..191
    const float* W = (c < 64) ? Wq : ((c < 128) ? Wk : Wv);
    const int col = c & 63;
    const int t = threadIdx.x;
    #pragma unroll
    for (int i = 0; i < 4; i++) {
        const int k = t + i * 256;
        wt[c * 1024 + k] = f2bf(W[(size_t)k * 64 + col]);
    }
}

// ---------------------------------------------------------------------------
// Kernel 1: QKV projection, bf16 MFMA, barrier-free K-loop.
// Grid 512 x 256 thr (4 waves). Block = 32 rows; wave w = cols 48w..48w+47.
// A-frags direct from global x (fp32->bf16 in regs); B-frags direct from
// L2-resident wt. LDS used only for the output-repack epilogue.
// Outputs: q (pre-scaled 0.125), k as bf16 [row][64]; v bf16 transposed [b][h][t].
// ---------------------------------------------------------------------------
__global__ __launch_bounds__(256, 2) void qkv_kernel(
    const float* __restrict__ x, const unsigned short* __restrict__ wt,
    unsigned short* __restrict__ qo, unsigned short* __restrict__ ko,
    unsigned short* __restrict__ vo)
{
    __shared__ __align__(16) unsigned short es[32 * 200];  // 12.8 KB epilogue

    const int t    = threadIdx.x;
    const int w    = t >> 6;
    const int lane = t & 63;
    const int l15  = lane & 15;
    const int quad = lane >> 4;
    const int r0   = blockIdx.x * 32;

    floatx4 acc[2][3];
    #pragma unroll
    for (int m = 0; m < 2; m++)
        #pragma unroll
        for (int n = 0; n < 3; n++) acc[m][n] = (floatx4)(0.0f);

    const float*          xa = x  + (size_t)(r0 + l15) * C_ + quad * 8;
    const unsigned short* wb = wt + (size_t)(w * 48 + l15) * C_ + quad * 8;

    #pragma unroll 2
    for (int k0 = 0; k0 < C_; k0 += 32) {
        const bf16x8 a0 = cvt8(*(const float4*)(xa + k0),
                               *(const float4*)(xa + k0 + 4));
        const bf16x8 a1 = cvt8(*(const float4*)(xa + 16 * C_ + k0),
                               *(const float4*)(xa + 16 * C_ + k0 + 4));
        const bf16x8 b0 = *(const bf16x8*)(wb + k0);
        const bf16x8 b1 = *(const bf16x8*)(wb + 16 * C_ + k0);
        const bf16x8 b2 = *(const bf16x8*)(wb + 32 * C_ + k0);
        acc[0][0] = MFMA(a0, b0, acc[0][0]);
        acc[1][0] = MFMA(a1, b0, acc[1][0]);
        acc[0][1] = MFMA(a0, b1, acc[0][1]);
        acc[1][1] = MFMA(a1, b1, acc[1][1]);
        acc[0][2] = MFMA(a0, b2, acc[0][2]);
        acc[1][2] = MFMA(a1, b2, acc[1][2]);
    }

    // ---- epilogue: repack through LDS, coalesced writes ----
    #pragma unroll
    for (int mt = 0; mt < 2; mt++)
        #pragma unroll
        for (int nt = 0; nt < 3; nt++) {
            const int col = w * 48 + nt * 16 + l15;
            const float sc = (col < 64) ? 0.125f : 1.0f;  // fold 1/sqrt(64) into q
            #pragma unroll
            for (int r = 0; r < 4; r++)
                es[(mt * 16 + quad * 4 + r) * 200 + col] =
                    f2bf(acc[mt][nt][r] * sc);
        }
    __syncthreads();

    { // q, k: [row][64] bf16
        const int row = t >> 3, oct = t & 7;
        *(uint4*)&qo[(size_t)(r0 + row) * 64 + oct * 8] =
            *(const uint4*)&es[row * 200 + oct * 8];
        *(uint4*)&ko[(size_t)(r0 + row) * 64 + oct * 8] =
            *(const uint4*)&es[row * 200 + 64 + oct * 8];
    }
    { // v: transposed [b][h][t]
        const int h = t >> 2, ts = (t & 3) * 8;
        const int b = r0 >> 11, tt = r0 & 2047;
        unsigned short tmp[8];
        #pragma unroll
        for (int j = 0; j < 8; j++) tmp[j] = es[(ts + j) * 200 + 128 + h];
        *(uint4*)&vo[((size_t)b * 64 + h) * 2048 + tt + ts] = *(uint4*)tmp;
    }
}

// ---------------------------------------------------------------------------
// Kernel 2: causal flash attention with ALiBi, bf16 MFMA.
// Single-wave blocks (64 thr), 16-row q-tile, 32-key steps.
// Grid 1024 = 8 batches x 128 q-tiles, heavy-first. K/V frags direct from
// global (L2-resident). LDS only for the 16x32 P C->A-layout round-trip.
// ---------------------------------------------------------------------------
__global__ __launch_bounds__(64) void attn_kernel(
    const unsigned short* __restrict__ q,
    const unsigned short* __restrict__ k,
    const unsigned short* __restrict__ vT,
    float* __restrict__ out)
{
    __shared__ __align__(16) unsigned short pT[16 * 40];  // stride 40 halfs (80 B)

    const int lane = threadIdx.x;
    const int l15  = lane & 15;
    const int quad = lane >> 4;
    const int b    = blockIdx.x & 7;
    const int qt   = 127 - (blockIdx.x >> 3);   // heavy tiles first
    const int q0   = qt * 16;
    const size_t kb = (size_t)b * T_ * 64;      // element offset of batch

    // Q A-fragments (held whole kernel; q pre-scaled by 0.125 in qkv)
    const bf16x8 qf0 = *(const bf16x8*)&q[kb + (size_t)(q0 + l15) * 64 + quad * 8];
    const bf16x8 qf1 = *(const bf16x8*)&q[kb + (size_t)(q0 + l15) * 64 + 32 + quad * 8];

    floatx4 O[4];
    #pragma unroll
    for (int i = 0; i < 4; i++) O[i] = (floatx4)(0.0f);
    float mrow[4], lrow[4];
    #pragma unroll
    for (int r = 0; r < 4; r++) { mrow[r] = -INFINITY; lrow[r] = 0.0f; }

    const int   nsteps = (q0 + 16 + 31) >> 5;
    const float bs  = 0.088388347648318447f;    // 2^-0.5 * 0.125 (alibi*scale)
    const int   ig0 = q0 + quad * 4;            // +r = global q row (in-batch)

    for (int s = 0; s < nsteps; s++) {
        const int j0 = s * 32;

        // ---- fragment loads for this step (global, L2-hot) ----
        bf16x8 kf[2][2], vf[4];
        #pragma unroll
        for (int nt2 = 0; nt2 < 2; nt2++)
            #pragma unroll
            for (int ks = 0; ks < 2; ks++)
                kf[nt2][ks] = *(const bf16x8*)
                    &k[kb + (size_t)(j0 + nt2 * 16 + l15) * 64 + ks * 32 + quad * 8];
        #pragma unroll
        for (int nt = 0; nt < 4; nt++)
            vf[nt] = *(const bf16x8*)
                &vT[((size_t)b * 64 + nt * 16 + l15) * 2048 + j0 + quad * 8];

        // ---- S = Q K^T ----
        floatx4 s2[2];
        #pragma unroll
        for (int nt2 = 0; nt2 < 2; nt2++) {
            floatx4 z = (floatx4)(0.0f);
            z = MFMA(qf0, kf[nt2][0], z);
            z = MFMA(qf1, kf[nt2][1], z);
            s2[nt2] = z;
        }

        __syncthreads();   // prev-iter pT read complete before overwrite

        // ---- ALiBi + causal mask + online softmax, write P^A to LDS ----
        #pragma unroll
        for (int r = 0; r < 4; r++) {
            const int ig = ig0 + r;
            float x0 = s2[0][r] + (float)(j0 + l15 - ig) * bs;
            float x1 = s2[1][r] + (float)(j0 + 16 + l15 - ig) * bs;
            if (j0 + l15 > ig)      x0 = -INFINITY;
            if (j0 + 16 + l15 > ig) x1 = -INFINITY;
            float mloc = fmaxf(x0, x1);
            #pragma unroll
            for (int off = 1; off < 16; off <<= 1)
                mloc = fmaxf(mloc, __shfl_xor(mloc, off));
            const float mnew  = fmaxf(mrow[r], mloc);
            const float alpha = __expf(mrow[r] - mnew);
            mrow[r] = mnew;
            const float p0 = __expf(x0 - mnew);
            const float p1 = __expf(x1 - mnew);
            float rs = p0 + p1;
            #pragma unroll
            for (int off = 1; off < 16; off <<= 1)
                rs += __shfl_xor(rs, off);
            lrow[r] = lrow[r] * alpha + rs;
            #pragma unroll
            for (int nt = 0; nt < 4; nt++) O[nt][r] *= alpha;
            pT[(quad * 4 + r) * 40 + l15]      = f2bf_fast(p0);
            pT[(quad * 4 + r) * 40 + 16 + l15] = f2bf_fast(p1);
        }
        __syncthreads();   // P writes visible before A-frag read

        // ---- O += P V ----
        const bf16x8 pf = *(const bf16x8*)&pT[l15 * 40 + quad * 8];
        #pragma unroll
        for (int nt = 0; nt < 4; nt++)
            O[nt] = MFMA(pf, vf[nt], O[nt]);
    }

    // ---- finalize ----
    #pragma unroll
    for (int r = 0; r < 4; r++) {
        const float inv = 1.0f / lrow[r];
        const int row = q0 + quad * 4 + r;
        #pragma unroll
        for (int nt = 0; nt < 4; nt++)
            out[kb + (size_t)row * 64 + nt * 16 + l15] = O[nt][r] * inv;
    }
}

extern "C" void kernel_launch(void* const* d_in, const int* in_sizes, int n_in,
                              void* d_out, int out_size, void* d_ws, size_t ws_size,
                              hipStream_t stream) {
    (void)in_sizes; (void)n_in; (void)out_size; (void)ws_size;
    const float* x  = (const float*)d_in[0];
    const float* Wq = (const float*)d_in[1];
    const float* Wk = (const float*)d_in[2];
    const float* Wv = (const float*)d_in[3];
    float* out = (float*)d_out;

    unsigned short* wt = (unsigned short*)d_ws;                 // [192][1024]
    unsigned short* qw = wt + 196608;                           // [M][64]
    unsigned short* kw = qw + (size_t)M_ * H_;                  // [M][64]
    unsigned short* vw = kw + (size_t)M_ * H_;                  // [B][64][2048]

    wprep_kernel<<<192, 256, 0, stream>>>(Wq, Wk, Wv, wt);
    qkv_kernel<<<M_ / 32, 256, 0, stream>>>(x, wt, qw, kw, vw);
    attn_kernel<<<B_ * 128, 64, 0, stream>>>(qw, kw, vw, out);
}

// Round 4
// 167.073 us; speedup vs baseline: 1.2195x; 1.2195x over previous
//
#include <hip/hip_runtime.h>
#include <hip/hip_bf16.h>
#include <math.h>

#define B_ 8
#define T_ 2048
#define C_ 1024
#define H_ 64
#define M_ (B_*T_)   // 16384 rows

typedef __attribute__((ext_vector_type(8))) short bf16x8;
typedef __attribute__((ext_vector_type(4))) float floatx4;

// fp32 -> bf16 round-to-nearest-even (cold paths)
static __device__ __forceinline__ unsigned short f2bf(float f) {
    union { float f; unsigned u; } v; v.f = f;
    unsigned r = v.u + 0x7fffu + ((v.u >> 16) & 1u);
    return (unsigned short)(r >> 16);
}
// fp32 -> bf16 round-half-up (2 VALU) for hot paths
static __device__ __forceinline__ unsigned short f2bf_fast(float f) {
    union { float f; unsigned u; } v; v.f = f;
    return (unsigned short)((v.u + 0x8000u) >> 16);
}
// pack two fp32 -> bf16 pair [hi|lo] in 3 VALU (add, add, v_perm)
static __device__ __forceinline__ unsigned pk2h(float lo, float hi) {
    union { float f; unsigned u; } a, b; a.f = lo; b.f = hi;
    return __builtin_amdgcn_perm(b.u + 0x8000u, a.u + 0x8000u, 0x07060302u);
}
static __device__ __forceinline__ bf16x8 cvt8(float4 f0, float4 f1) {
    union { uint4 u; bf16x8 v; } r;
    r.u.x = pk2h(f0.x, f0.y); r.u.y = pk2h(f0.z, f0.w);
    r.u.z = pk2h(f1.x, f1.y); r.u.w = pk2h(f1.z, f1.w);
    return r.v;
}

#define MFMA(a,b,c) __builtin_amdgcn_mfma_f32_16x16x32_bf16((a),(b),(c),0,0,0)

// ---------------------------------------------------------------------------
// Kernel 0: W prep -> wt2 in MFMA B-fragment order.
// wt2 flat index: ((tile*32 + kchunk)*64 + lane)*8, tile=0..11 (16 cols each,
// cols = q|k|v), kchunk=0..31 (32 k each). lane frag: [col=l15][k=quad*8+j].
// q-columns (tile 0..3) pre-scaled by 0.125.
// ---------------------------------------------------------------------------
__global__ __launch_bounds__(256) void wprep_kernel(
    const float* __restrict__ Wq, const float* __restrict__ Wk,
    const float* __restrict__ Wv, unsigned short* __restrict__ wt2)
{
    const int f    = blockIdx.x * 256 + threadIdx.x;  // 0..24575
    const int nt   = f >> 11;
    const int kc   = (f >> 6) & 31;
    const int lane = f & 63;
    const int l15  = lane & 15, quad = lane >> 4;
    const int col  = nt * 16 + l15;                   // 0..191
    const float* W = (col < 64) ? Wq : ((col < 128) ? Wk : Wv);
    const int   cw = col & 63;
    const float sc = (col < 64) ? 0.125f : 1.0f;
    unsigned short o[8];
    #pragma unroll
    for (int j = 0; j < 8; j++) {
        const int kk = kc * 32 + quad * 8 + j;
        o[j] = f2bf(W[(size_t)kk * 64 + cw] * sc);
    }
    *(uint4*)&wt2[(size_t)f * 8] = *(const uint4*)o;
}

// ---------------------------------------------------------------------------
// Kernel 1: QKV projection, bf16 MFMA, barrier-free K-loop.
// Grid 512 x 256 thr (4 waves). Block = 32 rows; wave w = cols 48w..48w+47.
// A-frags direct from global x (fp32->bf16 in regs); B-frags are single
// coalesced 1KB wave loads from fragment-ordered wt2.
// ---------------------------------------------------------------------------
__global__ __launch_bounds__(256) void qkv_kernel(
    const float* __restrict__ x, const unsigned short* __restrict__ wt2,
    unsigned short* __restrict__ qo, unsigned short* __restrict__ ko,
    unsigned short* __restrict__ vo)
{
    __shared__ __align__(16) unsigned short es[32 * 200];  // 12.8 KB epilogue

    const int t    = threadIdx.x;
    const int w    = t >> 6;
    const int lane = t & 63;
    const int l15  = lane & 15;
    const int quad = lane >> 4;
    const int r0   = blockIdx.x * 32;

    floatx4 acc[2][3];
    #pragma unroll
    for (int m = 0; m < 2; m++)
        #pragma unroll
        for (int n = 0; n < 3; n++) acc[m][n] = (floatx4)(0.0f);

    const float*          xa = x   + (size_t)(r0 + l15) * C_ + quad * 8;
    const unsigned short* wb = wt2 + (size_t)(w * 3) * 32 * 512 + lane * 8;

    #pragma unroll 2
    for (int kc = 0; kc < 32; kc++) {
        const int k0 = kc * 32;
        const bf16x8 a0 = cvt8(*(const float4*)(xa + k0),
                               *(const float4*)(xa + k0 + 4));
        const bf16x8 a1 = cvt8(*(const float4*)(xa + 16 * C_ + k0),
                               *(const float4*)(xa + 16 * C_ + k0 + 4));
        const bf16x8 b0 = *(const bf16x8*)(wb + (size_t)(0 * 32 + kc) * 512);
        const bf16x8 b1 = *(const bf16x8*)(wb + (size_t)(1 * 32 + kc) * 512);
        const bf16x8 b2 = *(const bf16x8*)(wb + (size_t)(2 * 32 + kc) * 512);
        acc[0][0] = MFMA(a0, b0, acc[0][0]);
        acc[1][0] = MFMA(a1, b0, acc[1][0]);
        acc[0][1] = MFMA(a0, b1, acc[0][1]);
        acc[1][1] = MFMA(a1, b1, acc[1][1]);
        acc[0][2] = MFMA(a0, b2, acc[0][2]);
        acc[1][2] = MFMA(a1, b2, acc[1][2]);
    }

    // ---- epilogue: repack through LDS, coalesced writes (scale pre-folded) --
    #pragma unroll
    for (int mt = 0; mt < 2; mt++)
        #pragma unroll
        for (int nt = 0; nt < 3; nt++) {
            const int col = w * 48 + nt * 16 + l15;
            #pragma unroll
            for (int r = 0; r < 4; r++)
                es[(mt * 16 + quad * 4 + r) * 200 + col] = f2bf(acc[mt][nt][r]);
        }
    __syncthreads();

    { // q, k: [row][64] bf16
        const int row = t >> 3, oct = t & 7;
        *(uint4*)&qo[(size_t)(r0 + row) * 64 + oct * 8] =
            *(const uint4*)&es[row * 200 + oct * 8];
        *(uint4*)&ko[(size_t)(r0 + row) * 64 + oct * 8] =
            *(const uint4*)&es[row * 200 + 64 + oct * 8];
    }
    { // v: transposed [b][h][t]
        const int h = t >> 2, ts = (t & 3) * 8;
        const int bb = r0 >> 11, tt = r0 & 2047;
        unsigned short tmp[8];
        #pragma unroll
        for (int j = 0; j < 8; j++) tmp[j] = es[(ts + j) * 200 + 128 + h];
        *(uint4*)&vo[((size_t)bb * 64 + h) * 2048 + tt + ts] = *(uint4*)tmp;
    }
}

// ---------------------------------------------------------------------------
// Kernel 2: causal flash attention with ALiBi, bf16 MFMA.
// 256 thr (4 waves) per block; 16-row q-tile; K-range split 4 ways across
// the waves (each wave: private online-softmax state, 64-key steps, no
// per-step barriers, per-wave pT region). Block-end LDS merge of partials.
// Grid 1024 = 8 batches x 128 q-tiles, heavy-first.
// ---------------------------------------------------------------------------
__global__ __launch_bounds__(256, 2) void attn_kernel(
    const unsigned short* __restrict__ q,
    const unsigned short* __restrict__ k,
    const unsigned short* __restrict__ vT,
    float* __restrict__ out)
{
    // pT region (during loop): 4 waves x 16x72 halfs = 9216 B at offset 0.
    // merge region (after barrier): Omg [4][16][64] f32 = 16384 B at 0,
    //                               mlg [4][2][16]  f32 =   512 B at 16384.
    __shared__ __align__(16) unsigned char smem[16384 + 512];
    unsigned short* pT  = (unsigned short*)smem;
    float*          Omg = (float*)smem;
    float*          mlg = (float*)(smem + 16384);

    const int t    = threadIdx.x;
    const int w    = t >> 6;
    const int lane = t & 63;
    const int l15  = lane & 15;
    const int quad = lane >> 4;
    const int b    = blockIdx.x & 7;
    const int qt   = 127 - (blockIdx.x >> 3);   // heavy tiles first
    const int q0   = qt * 16;
    const size_t kb = (size_t)b * T_ * 64;

    // Q A-fragments (scale folded into Wq)
    const bf16x8 qf0 = *(const bf16x8*)&q[kb + (size_t)(q0 + l15) * 64 + quad * 8];
    const bf16x8 qf1 = *(const bf16x8*)&q[kb + (size_t)(q0 + l15) * 64 + 32 + quad * 8];

    floatx4 O[4];
    #pragma unroll
    for (int i = 0; i < 4; i++) O[i] = (floatx4)(0.0f);
    float mrow[4], lrow[4];
    #pragma unroll
    for (int r = 0; r < 4; r++) { mrow[r] = -INFINITY; lrow[r] = 0.0f; }

    const int nk     = q0 + 16;
    const int nsteps = (nk + 63) >> 6;
    const int ns4    = (nsteps + 3) >> 2;
    const int sBeg   = w * ns4;
    const int sEnd   = min(sBeg + ns4, nsteps);
    const float bs   = 0.088388347648318447f;   // 2^-0.5 * 0.125
    const int   ig0  = q0 + quad * 4;
    unsigned short* pw = pT + w * 16 * 72;

    for (int s = sBeg; s < sEnd; s++) {
        const int j0 = s * 64;

        // K fragments (QK^T B-operand) and V^T fragments (PV B-operand)
        bf16x8 kf[4][2], vf[4][2];
        #pragma unroll
        for (int nt = 0; nt < 4; nt++) {
            #pragma unroll
            for (int ks = 0; ks < 2; ks++) {
                kf[nt][ks] = *(const bf16x8*)
                    &k[kb + (size_t)(j0 + nt * 16 + l15) * 64 + ks * 32 + quad * 8];
                vf[nt][ks] = *(const bf16x8*)
                    &vT[((size_t)b * 64 + nt * 16 + l15) * 2048 + j0 + ks * 32 + quad * 8];
            }
        }

        // ---- S = Q K^T over 64 keys ----
        floatx4 sc[4];
        #pragma unroll
        for (int nt = 0; nt < 4; nt++) {
            floatx4 z = (floatx4)(0.0f);
            z = MFMA(qf0, kf[nt][0], z);
            z = MFMA(qf1, kf[nt][1], z);
            sc[nt] = z;
        }

        // ---- ALiBi + causal + online softmax (deferred l-reduce) ----
        #pragma unroll
        for (int r = 0; r < 4; r++) {
            const int ig = ig0 + r;
            float xv[4];
            float mloc = -INFINITY;
            #pragma unroll
            for (int nt = 0; nt < 4; nt++) {
                const int j = j0 + nt * 16 + l15;
                float v2 = sc[nt][r] + (float)(j - ig) * bs;
                if (j > ig) v2 = -INFINITY;
                xv[nt] = v2;
                mloc = fmaxf(mloc, v2);
            }
            #pragma unroll
            for (int off = 1; off < 16; off <<= 1)
                mloc = fmaxf(mloc, __shfl_xor(mloc, off));
            const float mnew = fmaxf(mrow[r], mloc);
            const float mq   = (mnew == -INFINITY) ? 0.0f : mnew;
            const float alpha = __expf(mrow[r] - mq);
            mrow[r] = mnew;
            float ps = 0.0f;
            #pragma unroll
            for (int nt = 0; nt < 4; nt++) {
                const float p = __expf(xv[nt] - mq);
                ps += p;
                pw[(quad * 4 + r) * 72 + nt * 16 + l15] = f2bf_fast(p);
            }
            lrow[r] = lrow[r] * alpha + ps;     // per-lane partial; reduced at end
            #pragma unroll
            for (int nt = 0; nt < 4; nt++) O[nt][r] *= alpha;
        }

        // ---- O += P V  (same-wave DS in-order; no barrier) ----
        const bf16x8 pf0 = *(const bf16x8*)&pw[l15 * 72 + quad * 8];
        const bf16x8 pf1 = *(const bf16x8*)&pw[l15 * 72 + 32 + quad * 8];
        #pragma unroll
        for (int nt = 0; nt < 4; nt++) {
            O[nt] = MFMA(pf0, vf[nt][0], O[nt]);
            O[nt] = MFMA(pf1, vf[nt][1], O[nt]);
        }
    }

    // ---- reduce per-lane l partials across the 16 key-lanes ----
    #pragma unroll
    for (int r = 0; r < 4; r++)
        #pragma unroll
        for (int off = 1; off < 16; off <<= 1)
            lrow[r] += __shfl_xor(lrow[r], off);

    __syncthreads();   // all waves done with pT

    // ---- publish partial state ----
    #pragma unroll
    for (int nt = 0; nt < 4; nt++)
        #pragma unroll
        for (int r = 0; r < 4; r++)
            Omg[w * 1024 + (quad * 4 + r) * 64 + nt * 16 + l15] = O[nt][r];
    if (l15 == 0) {
        #pragma unroll
        for (int r = 0; r < 4; r++) {
            mlg[w * 32 + (quad * 4 + r)]      = mrow[r];
            mlg[w * 32 + 16 + (quad * 4 + r)] = lrow[r];
        }
    }
    __syncthreads();

    // ---- merge 4 partials, write output ----
    {
        const int row = t >> 4;          // 0..15
        const int hq  = (t & 15) << 2;   // 0..60
        float mstar = -INFINITY;
        #pragma unroll
        for (int w2 = 0; w2 < 4; w2++)
            mstar = fmaxf(mstar, mlg[w2 * 32 + row]);
        floatx4 oa = (floatx4)(0.0f);
        float lsum = 0.0f;
        #pragma unroll
        for (int w2 = 0; w2 < 4; w2++) {
            const float wg = __expf(mlg[w2 * 32 + row] - mstar);
            lsum += wg * mlg[w2 * 32 + 16 + row];
            const floatx4 ov = *(const floatx4*)&Omg[w2 * 1024 + row * 64 + hq];
            oa += wg * ov;
        }
        const float inv = 1.0f / lsum;
        *(floatx4*)&out[kb + (size_t)(q0 + row) * 64 + hq] = oa * inv;
    }
}

extern "C" void kernel_launch(void* const* d_in, const int* in_sizes, int n_in,
                              void* d_out, int out_size, void* d_ws, size_t ws_size,
                              hipStream_t stream) {
    (void)in_sizes; (void)n_in; (void)out_size; (void)ws_size;
    const float* x  = (const float*)d_in[0];
    const float* Wq = (const float*)d_in[1];
    const float* Wk = (const float*)d_in[2];
    const float* Wv = (const float*)d_in[3];
    float* out = (float*)d_out;

    unsigned short* wt2 = (unsigned short*)d_ws;                // [12][32][64][8]
    unsigned short* qw  = wt2 + 196608;                         // [M][64]
    unsigned short* kw  = qw + (size_t)M_ * H_;                 // [M][64]
    unsigned short* vw  = kw + (size_t)M_ * H_;                 // [B][64][2048]

    wprep_kernel<<<96, 256, 0, stream>>>(Wq, Wk, Wv, wt2);
    qkv_kernel<<<M_ / 32, 256, 0, stream>>>(x, wt2, qw, kw, vw);
    attn_kernel<<<B_ * 128, 256, 0, stream>>>(qw, kw, vw, out);
}